// Round 1
// baseline (93.778 us; speedup 1.0000x reference)
//
#include <hip/hip_runtime.h>

// CompositionalEmbeddings: out[b,s, 0:512]   = token_table[id]
//                          out[b,s, 512:1024] = cat_table[id]
// where cat_table = concat(op[10], var[10], const[10], struct[10], special[49960])
// and the category offsets (0,10,20,30,40) line up with the id ranges.
//
// Pure gather/copy -> memory-bound. One 256-thread block per token; each
// thread moves one float4 (16B). Lanes 0-127 handle the token half, lanes
// 128-255 the category half => wave-uniform branching (wave=64).

#define HALF_DIM 512
#define V4_PER_HALF (HALF_DIM / 4)   // 128 float4 per half-row

__global__ __launch_bounds__(256) void compemb_kernel(
    const int* __restrict__ ids,
    const float4* __restrict__ tok,     // [50000][128] float4
    const float4* __restrict__ op_t,    // [10][128]
    const float4* __restrict__ var_t,   // [10][128]
    const float4* __restrict__ cst_t,   // [10][128]
    const float4* __restrict__ str_t,   // [10][128]
    const float4* __restrict__ spc_t,   // [49960][128]
    float4* __restrict__ out,           // [n_tokens][256] float4
    int n_tokens)
{
    const int token = blockIdx.x;
    if (token >= n_tokens) return;

    const int id = ids[token];          // block-uniform -> scalar load
    const int t  = threadIdx.x;
    const int e  = t & (V4_PER_HALF - 1);   // element within the half-row

    const float4* src;
    long long row;
    if (t < V4_PER_HALF) {
        // token-embedding half (waves 0-1)
        src = tok;  row = id;
    } else {
        // category-embedding half (waves 2-3); id is wave-uniform
        if (id < 10)      { src = op_t;  row = id; }
        else if (id < 20) { src = var_t; row = id - 10; }
        else if (id < 30) { src = cst_t; row = id - 20; }
        else if (id < 40) { src = str_t; row = id - 30; }
        else              { src = spc_t; row = id - 40; }
    }

    out[(long long)token * 256 + t] = src[row * V4_PER_HALF + e];
}

extern "C" void kernel_launch(void* const* d_in, const int* in_sizes, int n_in,
                              void* d_out, int out_size, void* d_ws, size_t ws_size,
                              hipStream_t stream) {
    const int*    ids   = (const int*)   d_in[0];
    const float4* tok   = (const float4*)d_in[1];
    const float4* op_t  = (const float4*)d_in[2];
    const float4* var_t = (const float4*)d_in[3];
    const float4* cst_t = (const float4*)d_in[4];
    const float4* str_t = (const float4*)d_in[5];
    const float4* spc_t = (const float4*)d_in[6];
    float4* out = (float4*)d_out;

    const int n_tokens = in_sizes[0];          // 32 * 2048 = 65536
    compemb_kernel<<<n_tokens, 256, 0, stream>>>(
        ids, tok, op_t, var_t, cst_t, str_t, spc_t, out, n_tokens);
}

// Round 3
// 79.739 us; speedup vs baseline: 1.1761x; 1.1761x over previous
//
#include <hip/hip_runtime.h>

// CompositionalEmbeddings: out[b,s, 0:512]   = token_table[id]
//                          out[b,s, 512:1024] = cat_table[id]
// where cat_table = concat(op[10], var[10], const[10], struct[10], special[49960])
// and the category offsets (0,10,20,30,40) line up with the id ranges.
//
// Pure gather/copy -> memory-bound. One 256-thread block per token; each
// thread moves one float4 (16B). Lanes 0-127 handle the token half, lanes
// 128-255 the category half => wave-uniform branching (wave=64).
//
// Round 3: nontemporal stores via native clang ext_vector_type (HIP's
// float4 class type is rejected by __builtin_nontemporal_store). The
// 256 MB output is never re-read; streaming it past L2/L3 keeps the
// ~204 MB of embedding tables resident in the 256 MiB Infinity Cache, so
// gather reads become L3 hits and HBM traffic approaches the mandatory
// 268 MB of writes.

typedef float f32x4 __attribute__((ext_vector_type(4)));

#define HALF_DIM 512
#define V4_PER_HALF (HALF_DIM / 4)   // 128 float4 per half-row

__global__ __launch_bounds__(256) void compemb_kernel(
    const int* __restrict__ ids,
    const f32x4* __restrict__ tok,     // [50000][128] float4
    const f32x4* __restrict__ op_t,    // [10][128]
    const f32x4* __restrict__ var_t,   // [10][128]
    const f32x4* __restrict__ cst_t,   // [10][128]
    const f32x4* __restrict__ str_t,   // [10][128]
    const f32x4* __restrict__ spc_t,   // [49960][128]
    f32x4* __restrict__ out,           // [n_tokens][256] float4
    int n_tokens)
{
    const int token = blockIdx.x;
    if (token >= n_tokens) return;

    const int id = ids[token];          // block-uniform -> scalar load
    const int t  = threadIdx.x;
    const int e  = t & (V4_PER_HALF - 1);   // element within the half-row

    const f32x4* src;
    long long row;
    if (t < V4_PER_HALF) {
        // token-embedding half (waves 0-1)
        src = tok;  row = id;
    } else {
        // category-embedding half (waves 2-3); id is wave-uniform
        if (id < 10)      { src = op_t;  row = id; }
        else if (id < 20) { src = var_t; row = id - 10; }
        else if (id < 30) { src = cst_t; row = id - 20; }
        else if (id < 40) { src = str_t; row = id - 30; }
        else              { src = spc_t; row = id - 40; }
    }

    const f32x4 v = src[row * V4_PER_HALF + e];
    __builtin_nontemporal_store(v, &out[(long long)token * 256 + t]);
}

extern "C" void kernel_launch(void* const* d_in, const int* in_sizes, int n_in,
                              void* d_out, int out_size, void* d_ws, size_t ws_size,
                              hipStream_t stream) {
    const int*   ids   = (const int*)  d_in[0];
    const f32x4* tok   = (const f32x4*)d_in[1];
    const f32x4* op_t  = (const f32x4*)d_in[2];
    const f32x4* var_t = (const f32x4*)d_in[3];
    const f32x4* cst_t = (const f32x4*)d_in[4];
    const f32x4* str_t = (const f32x4*)d_in[5];
    const f32x4* spc_t = (const f32x4*)d_in[6];
    f32x4* out = (f32x4*)d_out;

    const int n_tokens = in_sizes[0];          // 32 * 2048 = 65536
    compemb_kernel<<<n_tokens, 256, 0, stream>>>(
        ids, tok, op_t, var_t, cst_t, str_t, spc_t, out, n_tokens);
}